// Round 1
// 1351.235 us; speedup vs baseline: 1.0507x; 1.0507x over previous
//
#include <hip/hip_runtime.h>
#include <math.h>

// Problem constants (match reference)
#define BB 32
#define SS 128
#define II 64
#define HH 1024
#define TT 4
#define HQ (HH / 4)   // H in float4 units

constexpr float DECAY  = 0.9f;
constexpr float THRESH = 1.0f;
constexpr float BETA   = 5.0f;

typedef float f4 __attribute__((ext_vector_type(4)));

// -----------------------------------------------------------------------------
// Kernel 1: drive[b,s,h] = sum_i x[b,s,i,h] * enc[i,h]
// Register-blocked: each thread computes 4 consecutive bs rows for one float4
// of h. enc fragment loaded ONCE per i and reused 4x (enc L2 traffic /4).
// x loads are nontemporal (pure 1 GiB stream, zero reuse) so they don't evict
// enc from L2. Result is stashed in out[b, s*TT+3, h] — the t=3 slot that
// lif_kernel reads (2 steps early) strictly before overwriting it.
// No workspace used at all.
// -----------------------------------------------------------------------------
__global__ __launch_bounds__(256) void drive_kernel(
    const f4* __restrict__ x,      // [B*S, I, HQ]
    const f4* __restrict__ enc,    // [I, HQ]
    f4* __restrict__ out)          // [B, S*T, HQ]
{
    const int tid = blockIdx.x * blockDim.x + threadIdx.x;  // [0, B*S/4 * HQ)
    const int hq  = tid & (HQ - 1);
    const int g   = tid >> 8;                               // 4-row group id
    const f4* xp = x + ((size_t)g * 4 * II) * HQ + hq;
    const f4* ep = enc + hq;

    f4 a0 = {0.f, 0.f, 0.f, 0.f};
    f4 a1 = {0.f, 0.f, 0.f, 0.f};
    f4 a2 = {0.f, 0.f, 0.f, 0.f};
    f4 a3 = {0.f, 0.f, 0.f, 0.f};

#pragma unroll 4
    for (int i = 0; i < II; ++i) {
        f4 ev = ep[(size_t)i * HQ];
        f4 x0 = __builtin_nontemporal_load(xp + (size_t)i * HQ);
        f4 x1 = __builtin_nontemporal_load(xp + (size_t)(II + i) * HQ);
        f4 x2 = __builtin_nontemporal_load(xp + (size_t)(2 * II + i) * HQ);
        f4 x3 = __builtin_nontemporal_load(xp + (size_t)(3 * II + i) * HQ);
        a0 = __builtin_elementwise_fma(x0, ev, a0);
        a1 = __builtin_elementwise_fma(x1, ev, a1);
        a2 = __builtin_elementwise_fma(x2, ev, a2);
        a3 = __builtin_elementwise_fma(x3, ev, a3);
    }

    const int bs = g << 2;              // first of 4 consecutive bs rows
    const int b  = bs >> 7;             // SS == 128
    const int s0 = bs & (SS - 1);       // rows s0..s0+3 stay within one b
    f4* dst = out + ((size_t)b * SS * TT + (size_t)(s0 * TT + 3)) * HQ + hq;
    dst[0]           = a0;              // slot (s0+r)*TT + 3, stride TT*HQ
    dst[TT * HQ]     = a1;
    dst[2 * TT * HQ] = a2;
    dst[3 * TT * HQ] = a3;
}

// -----------------------------------------------------------------------------
// Kernel 2: sequential LIF scan. One thread per (b,h) chain; 512 waves.
// Drive values read from out's t=3 slots with DEPTH-2 prefetch (load for s+2
// issued while s computes — hides ~900cy HBM/L3 latency under 2 steps of
// compute). Sigmoid via v_exp_f32 + v_rcp_f32 (~30cy dep chain per substep
// instead of ~90cy for precise expf + IEEE divide).
// Ordering: slot (4s+3) is read at step s-2 (register d0 by step s), and only
// overwritten by the SAME thread at step s, t=3 — program-order safe.
// -----------------------------------------------------------------------------
__global__ __launch_bounds__(64) void lif_kernel(
    float* __restrict__ out,       // [B, S*T, H]  (t=3 slots pre-seeded w/ drive)
    float* __restrict__ vfinal)    // [B, H]
{
    const int tid = blockIdx.x * blockDim.x + threadIdx.x;  // [0, B*H)
    const int h   = tid & (HH - 1);
    const int b   = tid >> 10;                              // H == 1024
    float* op = out + (size_t)b * SS * TT * HH + h;

    float v  = 0.f;
    float d0 = op[(size_t)3 * HH];                          // drive(s=0)
    float d1 = op[(size_t)7 * HH];                          // drive(s=1)

    for (int s = 0; s < SS; ++s) {
        float dn = 0.f;
        if (s + 2 < SS) dn = op[(size_t)((s + 2) * TT + 3) * HH];  // prefetch s+2
#pragma unroll
        for (int t = 0; t < TT; ++t) {
            v = fmaf(DECAY, v, d0);
            float az = fmaf(-BETA, v, BETA * THRESH);       // BETA*(THRESH - v)
            float e  = __expf(az);                          // exp(-BETA*(v-TH))
            float sp = __builtin_amdgcn_rcpf(1.f + e);      // sigmoid
            v = fmaf(-THRESH, sp, v);                       // subtractive reset
            op[(size_t)(s * TT + t) * HH] = sp;             // t=3 overwrites seed
        }
        d0 = d1;
        d1 = dn;
    }
    vfinal[tid] = v;
}

extern "C" void kernel_launch(void* const* d_in, const int* in_sizes, int n_in,
                              void* d_out, int out_size, void* d_ws, size_t ws_size,
                              hipStream_t stream) {
    const f4* x   = (const f4*)d_in[0];   // [B,S,I,H]
    const f4* enc = (const f4*)d_in[1];   // [I,H]
    float* out    = (float*)d_out;                        // [B,S*T,H] then [B,H]
    float* vfinal = out + (size_t)BB * SS * TT * HH;      // concatenated flat

    (void)d_ws; (void)ws_size;  // workspace intentionally unused

    {
        const int nthreads = (BB * SS / 4) * HQ;   // 262,144 threads
        drive_kernel<<<nthreads / 256, 256, 0, stream>>>(x, enc, (f4*)out);
    }
    {
        const int n = BB * HH;                     // 32,768 threads
        lif_kernel<<<n / 64, 64, 0, stream>>>(out, vfinal);
    }
}